// Round 2
// baseline (198.595 us; speedup 1.0000x reference)
//
#include <hip/hip_runtime.h>

#define B_   8
#define N_   6
#define DD_  41
#define FH_  8
#define FW_  22
#define C_   64
#define NXX  200
#define NXY  200
#define NZ_  1

// One block (64 threads = 1 wave = C channels) per (b,n,h,w) pixel.
// Geometry (bin-deciding math) in f64 to match the numpy reference's binning;
// feature weighting/accumulation in f32 (smooth, threshold is 2% of max).
__global__ __launch_bounds__(64) void lss_kernel(
    const float* __restrict__ depth_logits,
    const float* __restrict__ feats,
    const float* __restrict__ rots,
    const float* __restrict__ trans,
    const float* __restrict__ Kp,
    const float* __restrict__ Dc,
    const float* __restrict__ xip,
    float* __restrict__ out)
{
#pragma clang fp contract(off)
    const int pix = blockIdx.x;
    const int w = pix % FW_;
    const int h = (pix / FW_) % FH_;
    const int cam = pix / (FW_ * FH_);
    const int b = cam / N_;

    const double u0 = (double)Kp[cam * 4 + 2];
    const double v0 = (double)Kp[cam * 4 + 3];

    // mask test — exact small integers
    const double u0m = floor(u0 / 16.0);
    const double v0m = floor(v0 / 16.0);
    const double dxm = (double)w - u0m;
    const double dym = (double)h - v0m;
    if (dxm * dxm + dym * dym >= 9.0) return;   // radius = (min(8,22)-1)/2 = 3

    const int lane = threadIdx.x;

    __shared__ float p_lds[DD_];
    __shared__ int   off_lds[DD_];

    // ---- softmax over the 41 depth bins (f64; lanes 0..40 hold one logit)
    double logit = -1.0e300;
    if (lane < DD_)
        logit = (double)depth_logits[(((size_t)cam * DD_ + lane) * FH_ + h) * FW_ + w];
    double mx = logit;
    for (int s = 32; s; s >>= 1) mx = fmax(mx, __shfl_xor(mx, s));
    double e = (lane < DD_) ? exp(logit - mx) : 0.0;
    double ssum = e;
    for (int s = 32; s; s >>= 1) ssum += __shfl_xor(ssum, s);
    if (lane < DD_) p_lds[lane] = (float)(e / ssum);

    // ---- ray: iterative undistort + MEI unprojection (f64, uniform per block)
    const double g1 = (double)Kp[cam * 4 + 0];
    const double g2 = (double)Kp[cam * 4 + 1];
    const double k1 = (double)Dc[cam * 4 + 0];
    const double k2 = (double)Dc[cam * 4 + 1];
    const double p1 = (double)Dc[cam * 4 + 2];
    const double p2 = (double)Dc[cam * 4 + 3];
    const double xiv = (double)xip[cam];

    const double px = (double)w * (351.0 / 21.0);   // linspace(0,351,22)
    const double py = (double)h * (127.0 / 7.0);    // linspace(0,127,8)

    const double ppx = (px - u0) / g1;
    const double ppy = (py - v0) / g2;
    double pux = ppx, puy = ppy;
    for (int it = 0; it < 20; ++it) {
        double r2 = pux * pux + puy * puy;
        double r4 = r2 * r2;
        double denom = 1.0 + k1 * r2 + k2 * r4;
        double nx_ = (ppx - 2.0 * p1 * pux * puy - p2 * (r2 + 2.0 * pux * pux)) / denom;
        double ny_ = (ppy - 2.0 * p2 * pux * puy - p1 * (r2 + 2.0 * puy * puy)) / denom;
        pux = nx_; puy = ny_;
    }
    double r2 = pux * pux + puy * puy;
    double aq = r2 + 1.0;
    double bq = 2.0 * xiv * r2;
    double cq = xiv * xiv * r2 - 1.0;
    double Zs = (-bq + sqrt(bq * bq - 4.0 * aq * cq)) / (2.0 * aq);
    double rx = pux * (Zs + xiv);
    double ry = puy * (Zs + xiv);
    double rz = Zs;
    double nrm = sqrt(rx * rx + ry * ry + rz * rz);
    rx /= nrm; ry /= nrm; rz /= nrm;

    // ---- per-depth voxel offsets (lanes 0..40, f64 binning)
    if (lane < DD_) {
        double dval = 4.0 + (double)lane;                 // arange(4,45,1)
        double pcx = rx * dval, pcy = ry * dval, pcz = rz * dval;
        const float* R = rots + (size_t)cam * 9;
        double ex = (double)R[0] * pcx + (double)R[1] * pcy + (double)R[2] * pcz + (double)trans[cam * 3 + 0];
        double ey = (double)R[3] * pcx + (double)R[4] * pcy + (double)R[5] * pcz + (double)trans[cam * 3 + 1];
        double ez = (double)R[6] * pcx + (double)R[7] * pcy + (double)R[8] * pcz + (double)trans[cam * 3 + 2];
        // * [-1, 1, 1]
        double sx = -ex, sy = ey, sz = ez;
        // floor((p - (BX - DX/2)) / DX); BX-DX/2 = (-50,-50,-10) exact
        int ix = (int)floor((sx + 50.0) / 0.5);
        int iy = (int)floor((sy + 50.0) / 0.5);
        int iz = (int)floor((sz + 10.0) / 20.0);
        bool kept = (ix >= 0) & (ix < NXX) & (iy >= 0) & (iy < NXY) & (iz >= 0) & (iz < NZ_);
        off_lds[lane] = kept
            ? (int)(((b * (C_ * NZ_) + iz) * NXX + ix) * NXY + iy)
            : -1;
    }
    __syncthreads();

    // ---- scatter: thread = channel
    const float f = feats[((size_t)cam * C_ + lane) * (FH_ * FW_) + h * FW_ + w];
    const int cstride = NZ_ * NXX * NXY;
    float* outc = out + (size_t)lane * cstride;
    for (int d = 0; d < DD_; ++d) {
        int off = off_lds[d];
        if (off >= 0) atomicAdd(outc + off, p_lds[d] * f);
    }
}

extern "C" void kernel_launch(void* const* d_in, const int* in_sizes, int n_in,
                              void* d_out, int out_size, void* d_ws, size_t ws_size,
                              hipStream_t stream) {
    const float* depth_logits = (const float*)d_in[0];
    const float* feats        = (const float*)d_in[1];
    const float* rots         = (const float*)d_in[2];
    const float* trans        = (const float*)d_in[3];
    const float* Kp           = (const float*)d_in[4];
    const float* Dc           = (const float*)d_in[5];
    const float* xip          = (const float*)d_in[6];
    float* out = (float*)d_out;

    // atomics accumulate -> must zero every call (graph replays don't re-poison)
    hipMemsetAsync(out, 0, (size_t)out_size * sizeof(float), stream);

    dim3 grid(B_ * N_ * FH_ * FW_);
    dim3 block(64);
    lss_kernel<<<grid, block, 0, stream>>>(depth_logits, feats, rots, trans,
                                           Kp, Dc, xip, out);
}

// Round 3
// 157.197 us; speedup vs baseline: 1.2634x; 1.2634x over previous
//
#include <hip/hip_runtime.h>

#define DD_   41
#define FH_   8
#define FW_   22
#define NPIX  (FH_*FW_)          // 176
#define C_    64
#define NXX   200
#define NXY   200
#define NCAM  48                 // 8 batches x 6 cams
#define MAXACT 32                // record slots per camera (actual active = 25)
#define RECS_PER_BATCH (6*MAXACT*DD_)   // 7872
#define TILE  32
#define NTILE 7                  // ceil(200/32)
#define CG    16                 // channels per k2 block

__device__ __forceinline__ bool lss_mask(int h, int w, double u0m, double v0m) {
    double dx = (double)w - u0m, dy = (double)h - v0m;
    return dx * dx + dy * dy < 9.0;   // kept (radius = (min(8,22)-1)/2 = 3)
}

// ---- K0: feats [cam][c][hw] -> [cam][hw][c] so a point's channels are contiguous
__global__ __launch_bounds__(256) void k0_transpose(
    const float* __restrict__ feats, float* __restrict__ ft)
{
    int i = blockIdx.x * 256 + threadIdx.x;     // 48*176*64 = 540672 = 2112*256 exact
    int c = i & 63;
    int hw = (i >> 6) % NPIX;
    int cam = i / (64 * NPIX);
    ft[i] = feats[((size_t)cam * C_ + c) * NPIX + hw];
}

// ---- K1: one block per camera; f64 geometry (bin-exact vs numpy ref) -> point records
__global__ __launch_bounds__(256) void k1_points(
    const float* __restrict__ depth_logits,
    const float* __restrict__ rots,
    const float* __restrict__ trans,
    const float* __restrict__ Kp,
    const float* __restrict__ Dc,
    const float* __restrict__ xip,
    uint2* __restrict__ recs)
{
#pragma clang fp contract(off)
    const int cam = blockIdx.x;
    const int b = cam / 6, n = cam % 6;
    const int t = threadIdx.x;

    const double u0 = (double)Kp[cam * 4 + 2];
    const double v0 = (double)Kp[cam * 4 + 3];
    const double u0m = floor(u0 / 16.0), v0m = floor(v0 / 16.0);

    // deterministic rank among active pixels + total count (every thread computes)
    int na = 0, rank = -1;
    for (int i = 0; i < NPIX; ++i) {
        bool m = lss_mask(i / FW_, i % FW_, u0m, v0m);
        if (i == t) rank = m ? na : -1;
        na += m;
    }
    uint2* rb = recs + (size_t)b * RECS_PER_BATCH + (size_t)n * (MAXACT * DD_);

    if (t < NPIX && rank >= 0 && rank < MAXACT) {
        const int h = t / FW_, w = t % FW_;

        const double g1 = (double)Kp[cam * 4 + 0];
        const double g2 = (double)Kp[cam * 4 + 1];
        const double k1 = (double)Dc[cam * 4 + 0];
        const double k2 = (double)Dc[cam * 4 + 1];
        const double p1 = (double)Dc[cam * 4 + 2];
        const double p2 = (double)Dc[cam * 4 + 3];
        const double xiv = (double)xip[cam];

        const double px = (double)w * (351.0 / 21.0);   // linspace(0,351,22)
        const double py = (double)h * (127.0 / 7.0);    // linspace(0,127,8)

        const double ppx = (px - u0) / g1;
        const double ppy = (py - v0) / g2;
        double pux = ppx, puy = ppy;
        for (int it = 0; it < 20; ++it) {
            double r2 = pux * pux + puy * puy;
            double r4 = r2 * r2;
            double denom = 1.0 + k1 * r2 + k2 * r4;
            double nx_ = (ppx - 2.0 * p1 * pux * puy - p2 * (r2 + 2.0 * pux * pux)) / denom;
            double ny_ = (ppy - 2.0 * p2 * pux * puy - p1 * (r2 + 2.0 * puy * puy)) / denom;
            pux = nx_; puy = ny_;
        }
        double r2 = pux * pux + puy * puy;
        double aq = r2 + 1.0;
        double bq = 2.0 * xiv * r2;
        double cq = xiv * xiv * r2 - 1.0;
        double Zs = (-bq + sqrt(bq * bq - 4.0 * aq * cq)) / (2.0 * aq);
        double rx = pux * (Zs + xiv);
        double ry = puy * (Zs + xiv);
        double rz = Zs;
        double nrm = sqrt(rx * rx + ry * ry + rz * rz);
        rx /= nrm; ry /= nrm; rz /= nrm;

        // softmax over 41 depth bins (f64, two-pass, serial ascending like ref)
        const float* lg = depth_logits + (size_t)cam * DD_ * NPIX + t;  // stride NPIX per d
        double mx = -1.0e300;
        for (int d = 0; d < DD_; ++d) mx = fmax(mx, (double)lg[d * NPIX]);
        double ssum = 0.0;
        for (int d = 0; d < DD_; ++d) ssum += exp((double)lg[d * NPIX] - mx);

        const float* R = rots + (size_t)cam * 9;
        const double T0 = (double)trans[cam * 3 + 0];
        const double T1 = (double)trans[cam * 3 + 1];
        const double T2 = (double)trans[cam * 3 + 2];

        for (int d = 0; d < DD_; ++d) {
            double wgt = exp((double)lg[d * NPIX] - mx) / ssum;
            double dval = 4.0 + (double)d;
            double pcx = rx * dval, pcy = ry * dval, pcz = rz * dval;
            double ex = (double)R[0] * pcx + (double)R[1] * pcy + (double)R[2] * pcz + T0;
            double ey = (double)R[3] * pcx + (double)R[4] * pcy + (double)R[5] * pcz + T1;
            double ez = (double)R[6] * pcx + (double)R[7] * pcy + (double)R[8] * pcz + T2;
            double sx = -ex, sy = ey, sz = ez;   // * [-1,1,1]
            int ix = (int)floor((sx + 50.0) / 0.5);
            int iy = (int)floor((sy + 50.0) / 0.5);
            int iz = (int)floor((sz + 10.0) / 20.0);
            bool kept = (ix >= 0) & (ix < NXX) & (iy >= 0) & (iy < NXY) & (iz == 0);
            unsigned meta = kept
                ? ((unsigned)iy | ((unsigned)ix << 8) | ((unsigned)t << 16) | ((unsigned)n << 24))
                : 0xFFFFFFFFu;
            rb[rank * DD_ + d] = make_uint2(meta, __float_as_uint((float)wgt));
        }
    }

    // sentinel-fill unused rank slots so every record is written every call
    int fillstart = na < MAXACT ? na : MAXACT;
    int nfill = (MAXACT - fillstart) * DD_;
    for (int idx = t; idx < nfill; idx += 256) {
        int r = fillstart + idx / DD_;
        int d = idx % DD_;
        rb[r * DD_ + d] = make_uint2(0xFFFFFFFFu, 0u);
    }
}

// ---- K2: tiled gather; writes the ENTIRE output (replaces memset), no global atomics
__global__ __launch_bounds__(256) void k2_splat(
    const uint2* __restrict__ recs,
    const float* __restrict__ ft,
    float* __restrict__ out)
{
    const int t49 = blockIdx.x;          // tile id 0..48
    const int cg  = blockIdx.y;          // channel group 0..3
    const int b   = blockIdx.z;          // batch 0..7
    const int txv = t49 / NTILE, tyv = t49 % NTILE;
    const int ix0 = txv * TILE, iy0 = tyv * TILE;
    const int tid = threadIdx.x;
    const int cbase = cg * CG;

    __shared__ float tile[CG][TILE * TILE];   // 64 KiB
    for (int i = tid; i < CG * TILE * TILE; i += 256) ((float*)tile)[i] = 0.0f;
    __syncthreads();

    const uint2* rb = recs + (size_t)b * RECS_PER_BATCH;
    for (int i = tid; i < RECS_PER_BATCH; i += 256) {
        uint2 r = rb[i];
        unsigned meta = r.x;
        unsigned iy = meta & 255u;
        unsigned ix = (meta >> 8) & 255u;       // sentinel -> 255 -> never in-tile
        if ((ix - (unsigned)ix0) < (unsigned)TILE && (iy - (unsigned)iy0) < (unsigned)TILE) {
            int hw = (meta >> 16) & 255;
            int n  = (meta >> 24) & 7;
            float wgt = __uint_as_float(r.y);
            const float4* fp = (const float4*)(ft +
                (((size_t)(b * 6 + n) * NPIX + hw) * C_ + cbase));
            int vloc = (ix - ix0) * TILE + (iy - iy0);
            #pragma unroll
            for (int q = 0; q < 4; ++q) {
                float4 f = fp[q];
                atomicAdd(&tile[q * 4 + 0][vloc], wgt * f.x);
                atomicAdd(&tile[q * 4 + 1][vloc], wgt * f.y);
                atomicAdd(&tile[q * 4 + 2][vloc], wgt * f.z);
                atomicAdd(&tile[q * 4 + 3][vloc], wgt * f.w);
            }
        }
    }
    __syncthreads();

    // coalesced float4 writes; bounds: ix rows >=200 skipped, iy cut is multiple of 4
    for (int i = tid; i < CG * TILE * (TILE / 4); i += 256) {
        int c   = i / (TILE * TILE / 4);
        int rr  = i % (TILE * TILE / 4);
        int ixl = rr / (TILE / 4);
        int iyq = (rr % (TILE / 4)) * 4;
        int ixg = ix0 + ixl, iyg = iy0 + iyq;
        if (ixg < NXX && iyg < NXY) {
            float4 v = *(const float4*)&tile[c][ixl * TILE + iyq];
            *(float4*)&out[(((size_t)b * C_ + cbase + c) * NXX + ixg) * NXY + iyg] = v;
        }
    }
}

extern "C" void kernel_launch(void* const* d_in, const int* in_sizes, int n_in,
                              void* d_out, int out_size, void* d_ws, size_t ws_size,
                              hipStream_t stream) {
    const float* depth_logits = (const float*)d_in[0];
    const float* feats        = (const float*)d_in[1];
    const float* rots         = (const float*)d_in[2];
    const float* trans        = (const float*)d_in[3];
    const float* Kp           = (const float*)d_in[4];
    const float* Dc           = (const float*)d_in[5];
    const float* xip          = (const float*)d_in[6];
    float* out = (float*)d_out;

    // workspace layout
    uint2* recs = (uint2*)d_ws;                                    // 8*7872*8 = 503808 B
    float* ft   = (float*)((char*)d_ws + (size_t)8 * RECS_PER_BATCH * 8);  // 2162688 B

    k0_transpose<<<dim3(2112), dim3(256), 0, stream>>>(feats, ft);
    k1_points<<<dim3(NCAM), dim3(256), 0, stream>>>(depth_logits, rots, trans,
                                                    Kp, Dc, xip, recs);
    k2_splat<<<dim3(NTILE * NTILE, C_ / CG, 8), dim3(256), 0, stream>>>(recs, ft, out);
}

// Round 4
// 122.006 us; speedup vs baseline: 1.6277x; 1.2884x over previous
//
#include <hip/hip_runtime.h>

#define DD_   41
#define FH_   8
#define FW_   22
#define NPIX  176
#define C_    64
#define NXX   200
#define NXY   200
#define NCAM  48
#define MAXACT 32
#define RECS_PER_BATCH (6*MAXACT*DD_)   // 7872
#define TX    8      // tile extent in ix
#define TY    32     // tile extent in iy (32 floats = 128B rows, full-line stores)
#define NTX   25     // 200/8 exact
#define NTY   7      // ceil(200/32)
#define CG    16     // channels per k2 block
#define QCAP  1536   // queue slots (worst-case per-tile hits ~750 for this geometry)

__device__ __forceinline__ bool lss_mask(int h, int w, double u0m, double v0m) {
    double dx = (double)w - u0m, dy = (double)h - v0m;
    return dx * dx + dy * dy < 9.0;   // kept (radius = (min(8,22)-1)/2 = 3)
}

// ---- K01: fused per-camera feats transpose (LDS, coalesced both ways) + f64
//          geometry emitting fixed-slot point records (bin-exact vs numpy ref)
__global__ __launch_bounds__(256) void k01_prep(
    const float* __restrict__ depth_logits,
    const float* __restrict__ feats,
    const float* __restrict__ rots,
    const float* __restrict__ trans,
    const float* __restrict__ Kp,
    const float* __restrict__ Dc,
    const float* __restrict__ xip,
    float* __restrict__ ft,
    uint2* __restrict__ recs)
{
#pragma clang fp contract(off)
    const int cam = blockIdx.x;
    const int b = cam / 6, n = cam % 6;
    const int t = threadIdx.x;

    // ---- transpose feats[cam][c][hw] -> ft[cam][hw][c] via LDS (pad 177)
    __shared__ float lds[C_ * 177];
    const float* fsrc = feats + (size_t)cam * (C_ * NPIX);
    for (int i4 = t; i4 < (C_ * NPIX) / 4; i4 += 256) {
        float4 v = ((const float4*)fsrc)[i4];
        int c = (i4 * 4) / NPIX, hw = (i4 * 4) % NPIX;   // NPIX%4==0: stays in row
        float* p = &lds[c * 177 + hw];
        p[0] = v.x; p[1] = v.y; p[2] = v.z; p[3] = v.w;
    }
    __syncthreads();
    float* fdst = ft + (size_t)cam * (NPIX * C_);
    for (int i4 = t; i4 < (NPIX * C_) / 4; i4 += 256) {
        int hw = (i4 * 4) / C_, c = (i4 * 4) % C_;       // c multiple of 4
        float4 v;
        v.x = lds[(c + 0) * 177 + hw];
        v.y = lds[(c + 1) * 177 + hw];
        v.z = lds[(c + 2) * 177 + hw];
        v.w = lds[(c + 3) * 177 + hw];
        ((float4*)fdst)[i4] = v;
    }

    // ---- geometry (f64, identical to passing Round-2/3 math)
    const double u0 = (double)Kp[cam * 4 + 2];
    const double v0 = (double)Kp[cam * 4 + 3];
    const double u0m = floor(u0 / 16.0), v0m = floor(v0 / 16.0);

    int na = 0, rank = -1;
    for (int i = 0; i < NPIX; ++i) {
        bool m = lss_mask(i / FW_, i % FW_, u0m, v0m);
        if (i == t) rank = m ? na : -1;
        na += m;
    }
    uint2* rb = recs + (size_t)b * RECS_PER_BATCH + (size_t)n * (MAXACT * DD_);

    if (t < NPIX && rank >= 0 && rank < MAXACT) {
        const int h = t / FW_, w = t % FW_;

        const double g1 = (double)Kp[cam * 4 + 0];
        const double g2 = (double)Kp[cam * 4 + 1];
        const double k1 = (double)Dc[cam * 4 + 0];
        const double k2 = (double)Dc[cam * 4 + 1];
        const double p1 = (double)Dc[cam * 4 + 2];
        const double p2 = (double)Dc[cam * 4 + 3];
        const double xiv = (double)xip[cam];

        const double px = (double)w * (351.0 / 21.0);   // linspace(0,351,22)
        const double py = (double)h * (127.0 / 7.0);    // linspace(0,127,8)

        const double ppx = (px - u0) / g1;
        const double ppy = (py - v0) / g2;
        double pux = ppx, puy = ppy;
        for (int it = 0; it < 20; ++it) {
            double r2 = pux * pux + puy * puy;
            double r4 = r2 * r2;
            double denom = 1.0 + k1 * r2 + k2 * r4;
            double nx_ = (ppx - 2.0 * p1 * pux * puy - p2 * (r2 + 2.0 * pux * pux)) / denom;
            double ny_ = (ppy - 2.0 * p2 * pux * puy - p1 * (r2 + 2.0 * puy * puy)) / denom;
            pux = nx_; puy = ny_;
        }
        double r2 = pux * pux + puy * puy;
        double aq = r2 + 1.0;
        double bq = 2.0 * xiv * r2;
        double cq = xiv * xiv * r2 - 1.0;
        double Zs = (-bq + sqrt(bq * bq - 4.0 * aq * cq)) / (2.0 * aq);
        double rx = pux * (Zs + xiv);
        double ry = puy * (Zs + xiv);
        double rz = Zs;
        double nrm = sqrt(rx * rx + ry * ry + rz * rz);
        rx /= nrm; ry /= nrm; rz /= nrm;

        const float* lg = depth_logits + (size_t)cam * DD_ * NPIX + t;
        double mx = -1.0e300;
        for (int d = 0; d < DD_; ++d) mx = fmax(mx, (double)lg[d * NPIX]);
        double ssum = 0.0;
        for (int d = 0; d < DD_; ++d) ssum += exp((double)lg[d * NPIX] - mx);

        const float* R = rots + (size_t)cam * 9;
        const double T0 = (double)trans[cam * 3 + 0];
        const double T1 = (double)trans[cam * 3 + 1];
        const double T2 = (double)trans[cam * 3 + 2];

        for (int d = 0; d < DD_; ++d) {
            double wgt = exp((double)lg[d * NPIX] - mx) / ssum;
            double dval = 4.0 + (double)d;
            double pcx = rx * dval, pcy = ry * dval, pcz = rz * dval;
            double ex = (double)R[0] * pcx + (double)R[1] * pcy + (double)R[2] * pcz + T0;
            double ey = (double)R[3] * pcx + (double)R[4] * pcy + (double)R[5] * pcz + T1;
            double ez = (double)R[6] * pcx + (double)R[7] * pcy + (double)R[8] * pcz + T2;
            double sx = -ex, sy = ey, sz = ez;   // * [-1,1,1]
            int ix = (int)floor((sx + 50.0) / 0.5);
            int iy = (int)floor((sy + 50.0) / 0.5);
            int iz = (int)floor((sz + 10.0) / 20.0);
            bool kept = (ix >= 0) & (ix < NXX) & (iy >= 0) & (iy < NXY) & (iz == 0);
            unsigned meta = kept
                ? ((unsigned)iy | ((unsigned)ix << 8) | ((unsigned)t << 16) | ((unsigned)n << 24))
                : 0xFFFFFFFFu;
            rb[rank * DD_ + d] = make_uint2(meta, __float_as_uint((float)wgt));
        }
    }

    // sentinel-fill unused rank slots (full rewrite every call)
    int fillstart = na < MAXACT ? na : MAXACT;
    int nfill = (MAXACT - fillstart) * DD_;
    for (int idx = t; idx < nfill; idx += 256) {
        int r = fillstart + idx / DD_;
        int d = idx % DD_;
        rb[r * DD_ + d] = make_uint2(0xFFFFFFFFu, 0u);
    }
}

// ---- K2: scan(ILP-4) -> LDS queue compaction -> dense process -> streamed write.
//      Writes the ENTIRE output (no memset needed); no global atomics.
__global__ __launch_bounds__(256) void k2_splat(
    const uint2* __restrict__ recs,
    const float* __restrict__ ft,
    float* __restrict__ out)
{
    const int tl = blockIdx.x;           // 0..174
    const int cg = blockIdx.y;           // 0..3
    const int b  = blockIdx.z;           // 0..7
    const int ix0 = (tl / NTY) * TX;
    const int iy0 = (tl % NTY) * TY;
    const int tid = threadIdx.x;
    const int cbase = cg * CG;

    __shared__ float tile[CG][TX * TY];  // 16 KiB
    __shared__ uint2 queue[QCAP];        // 12 KiB
    __shared__ int qcnt;

    for (int i = tid; i < CG * TX * TY / 4; i += 256)
        ((float4*)tile)[i] = make_float4(0.f, 0.f, 0.f, 0.f);
    if (tid == 0) qcnt = 0;
    __syncthreads();

    // Phase A: cooperative scan, 4 records per thread-iteration (2x uint4 loads)
    const uint2* rb = recs + (size_t)b * RECS_PER_BATCH;
    for (int base = tid * 4; base < RECS_PER_BATCH; base += 1024) {
        uint4 ra = *(const uint4*)(rb + base);
        uint4 rc = *(const uint4*)(rb + base + 2);
        unsigned ms[4] = {ra.x, ra.z, rc.x, rc.z};
        unsigned ws[4] = {ra.y, ra.w, rc.y, rc.w};
        #pragma unroll
        for (int k = 0; k < 4; ++k) {
            unsigned meta = ms[k];
            unsigned diy = (meta & 255u) - (unsigned)iy0;
            unsigned dix = ((meta >> 8) & 255u) - (unsigned)ix0;   // sentinel->255: fails
            if (dix < (unsigned)TX && diy < (unsigned)TY) {
                int pos = atomicAdd(&qcnt, 1);
                if (pos < QCAP)
                    queue[pos] = make_uint2((dix * TY + diy) | ((meta >> 16) << 8), ws[k]);
            }
        }
    }
    __syncthreads();
    const int qn = min(qcnt, QCAP);

    // Phase B: dense per-hit accumulate (thread = hit record, CG channels each)
    for (int q = tid; q < qn; q += 256) {
        uint2 e = queue[q];
        int vloc = e.x & 255;
        int hw   = (e.x >> 8) & 255;
        int n    = (e.x >> 16) & 255;
        float wgt = __uint_as_float(e.y);
        const float4* fp = (const float4*)(ft +
            (((size_t)(b * 6 + n) * NPIX + hw) * C_ + cbase));
        #pragma unroll
        for (int qd = 0; qd < CG / 4; ++qd) {
            float4 f = fp[qd];
            atomicAdd(&tile[qd * 4 + 0][vloc], wgt * f.x);
            atomicAdd(&tile[qd * 4 + 1][vloc], wgt * f.y);
            atomicAdd(&tile[qd * 4 + 2][vloc], wgt * f.z);
            atomicAdd(&tile[qd * 4 + 3][vloc], wgt * f.w);
        }
    }
    __syncthreads();

    // Phase C: stream tile to out; 128B full-line rows (TY=32)
    for (int i = tid; i < CG * TX * (TY / 4); i += 256) {
        int c   = i / (TX * TY / 4);
        int rr  = i % (TX * TY / 4);
        int ixl = rr / (TY / 4);
        int iyq = (rr % (TY / 4)) * 4;
        int iyg = iy0 + iyq;
        if (iyg < NXY) {   // ix always in range: 25*8 = 200 exact
            float4 v = *(const float4*)&tile[c][ixl * TY + iyq];
            *(float4*)&out[(((size_t)b * C_ + cbase + c) * NXX + (ix0 + ixl)) * NXY + iyg] = v;
        }
    }
}

extern "C" void kernel_launch(void* const* d_in, const int* in_sizes, int n_in,
                              void* d_out, int out_size, void* d_ws, size_t ws_size,
                              hipStream_t stream) {
    const float* depth_logits = (const float*)d_in[0];
    const float* feats        = (const float*)d_in[1];
    const float* rots         = (const float*)d_in[2];
    const float* trans        = (const float*)d_in[3];
    const float* Kp           = (const float*)d_in[4];
    const float* Dc           = (const float*)d_in[5];
    const float* xip          = (const float*)d_in[6];
    float* out = (float*)d_out;

    uint2* recs = (uint2*)d_ws;                                           // 503808 B
    float* ft   = (float*)((char*)d_ws + (size_t)8 * RECS_PER_BATCH * 8); // 2162688 B

    k01_prep<<<dim3(NCAM), dim3(256), 0, stream>>>(depth_logits, feats, rots, trans,
                                                   Kp, Dc, xip, ft, recs);
    k2_splat<<<dim3(NTX * NTY, C_ / CG, 8), dim3(256), 0, stream>>>(recs, ft, out);
}

// Round 5
// 117.225 us; speedup vs baseline: 1.6941x; 1.0408x over previous
//
#include <hip/hip_runtime.h>

#define DD_   41
#define FH_   8
#define FW_   22
#define NPIX  176
#define C_    64
#define NXX   200
#define NXY   200
#define NCAM  48
#define MAXACT 32
#define RECS_PER_BATCH (6*MAXACT*DD_)   // 7872
#define NRECS  (8*RECS_PER_BATCH)       // 62976
#define TX    8
#define TY    32
#define NTX   25                        // 200/8
#define NTY   7                         // ceil(200/32)
#define NTILE (NTX*NTY)                 // 175
#define NBUCKET (8*NTILE)               // 1400
#define CG    16

// ---- K0: per-camera feats transpose [c][hw]->[hw][c] via LDS; block 0 zeros counts
__global__ __launch_bounds__(256) void k0_prep(
    const float* __restrict__ feats, float* __restrict__ ft, int* __restrict__ counts)
{
    const int cam = blockIdx.x;
    const int t = threadIdx.x;
    if (cam == 0) for (int i = t; i < NBUCKET; i += 256) counts[i] = 0;

    __shared__ float lds[C_ * 177];
    const float* fsrc = feats + (size_t)cam * (C_ * NPIX);
    for (int i4 = t; i4 < (C_ * NPIX) / 4; i4 += 256) {
        float4 v = ((const float4*)fsrc)[i4];
        int c = (i4 * 4) / NPIX, hw = (i4 * 4) % NPIX;
        float* p = &lds[c * 177 + hw];
        p[0] = v.x; p[1] = v.y; p[2] = v.z; p[3] = v.w;
    }
    __syncthreads();
    float* fdst = ft + (size_t)cam * (NPIX * C_);
    for (int i4 = t; i4 < (NPIX * C_) / 4; i4 += 256) {
        int hw = (i4 * 4) / C_, c = (i4 * 4) % C_;
        float4 v;
        v.x = lds[(c + 0) * 177 + hw];
        v.y = lds[(c + 1) * 177 + hw];
        v.z = lds[(c + 2) * 177 + hw];
        v.w = lds[(c + 3) * 177 + hw];
        ((float4*)fdst)[i4] = v;
    }
}

// ---- K1: one 64-thread wave per (cam,pixel). Ballot rank, f32 shuffle softmax,
//          f64 geometry (bit-identical chain to the passing rounds), record emit,
//          per-bucket count atomics.
__global__ __launch_bounds__(64) void k1_geom(
    const float* __restrict__ depth_logits,
    const float* __restrict__ rots,
    const float* __restrict__ trans,
    const float* __restrict__ Kp,
    const float* __restrict__ Dc,
    const float* __restrict__ xip,
    uint2* __restrict__ recs,
    int* __restrict__ counts)
{
#pragma clang fp contract(off)
    const int gb = blockIdx.x;           // 0..8447
    const int pix = gb % NPIX;
    const int cam = gb / NPIX;
    const int b = cam / 6, n = cam % 6;
    const int lane = threadIdx.x;

    const double u0 = (double)Kp[cam * 4 + 2];
    const double v0 = (double)Kp[cam * 4 + 3];
    const int u0m = (int)floor(u0 / 16.0);
    const int v0m = (int)floor(v0 / 16.0);

    // masks for pixels lane, lane+64, lane+128 (int-exact)
    auto maskf = [&](int p) -> bool {
        if (p >= NPIX) return false;
        int dx = (p % FW_) - u0m, dy = (p / FW_) - v0m;
        return dx * dx + dy * dy < 9;    // radius=3
    };
    unsigned long long b0 = __ballot(maskf(lane));
    unsigned long long b1 = __ballot(maskf(lane + 64));
    unsigned long long b2 = __ballot(maskf(lane + 128));
    const int na = __popcll(b0) + __popcll(b1) + __popcll(b2);

    bool mymask; int rank;
    if (pix < 64) {
        mymask = (b0 >> pix) & 1;
        rank = __popcll(b0 & ((1ull << pix) - 1));
    } else if (pix < 128) {
        int p = pix - 64;
        mymask = (b1 >> p) & 1;
        rank = __popcll(b0) + __popcll(b1 & ((1ull << p) - 1));
    } else {
        int p = pix - 128;
        mymask = (b2 >> p) & 1;
        rank = __popcll(b0) + __popcll(b1) + __popcll(b2 & ((1ull << p) - 1));
    }

    uint2* rbcam = recs + (size_t)cam * (MAXACT * DD_);
    if (pix == 0) {   // one wave per cam sentinel-fills unused rank slots
        for (int r = (na < MAXACT ? na : MAXACT); r < MAXACT; ++r)
            if (lane < DD_) rbcam[r * DD_ + lane] = make_uint2(0xFFFFFFFFu, 0u);
    }
    if (!mymask || rank >= MAXACT) return;

    // ---- softmax (f32, shuffle reduce; weights are smooth — f64 not needed)
    const float* lg = depth_logits + (size_t)cam * DD_ * NPIX + pix;
    float logit = (lane < DD_) ? lg[lane * NPIX] : -3.0e38f;
    float mx = logit;
    for (int s = 32; s; s >>= 1) mx = fmaxf(mx, __shfl_xor(mx, s));
    float ev = (lane < DD_) ? expf(logit - mx) : 0.0f;
    float ssum = ev;
    for (int s = 32; s; s >>= 1) ssum += __shfl_xor(ssum, s);
    const float wgt = ev / ssum;

    // ---- f64 geometry (same expression order as the passing kernel)
    const int h = pix / FW_, w = pix % FW_;
    const double g1 = (double)Kp[cam * 4 + 0];
    const double g2 = (double)Kp[cam * 4 + 1];
    const double k1 = (double)Dc[cam * 4 + 0];
    const double k2 = (double)Dc[cam * 4 + 1];
    const double p1 = (double)Dc[cam * 4 + 2];
    const double p2 = (double)Dc[cam * 4 + 3];
    const double xiv = (double)xip[cam];

    const double px = (double)w * (351.0 / 21.0);
    const double py = (double)h * (127.0 / 7.0);
    const double ppx = (px - u0) / g1;
    const double ppy = (py - v0) / g2;
    double pux = ppx, puy = ppy;
    for (int it = 0; it < 20; ++it) {
        double r2 = pux * pux + puy * puy;
        double r4 = r2 * r2;
        double denom = 1.0 + k1 * r2 + k2 * r4;
        double nx_ = (ppx - 2.0 * p1 * pux * puy - p2 * (r2 + 2.0 * pux * pux)) / denom;
        double ny_ = (ppy - 2.0 * p2 * pux * puy - p1 * (r2 + 2.0 * puy * puy)) / denom;
        pux = nx_; puy = ny_;
    }
    double r2 = pux * pux + puy * puy;
    double aq = r2 + 1.0;
    double bq = 2.0 * xiv * r2;
    double cq = xiv * xiv * r2 - 1.0;
    double Zs = (-bq + sqrt(bq * bq - 4.0 * aq * cq)) / (2.0 * aq);
    double rx = pux * (Zs + xiv);
    double ry = puy * (Zs + xiv);
    double rz = Zs;
    double nrm = sqrt(rx * rx + ry * ry + rz * rz);
    rx /= nrm; ry /= nrm; rz /= nrm;

    if (lane < DD_) {
        const float* R = rots + (size_t)cam * 9;
        double dval = 4.0 + (double)lane;
        double pcx = rx * dval, pcy = ry * dval, pcz = rz * dval;
        double ex = (double)R[0] * pcx + (double)R[1] * pcy + (double)R[2] * pcz + (double)trans[cam * 3 + 0];
        double ey = (double)R[3] * pcx + (double)R[4] * pcy + (double)R[5] * pcz + (double)trans[cam * 3 + 1];
        double ez = (double)R[6] * pcx + (double)R[7] * pcy + (double)R[8] * pcz + (double)trans[cam * 3 + 2];
        double sx = -ex, sy = ey, sz = ez;   // * [-1,1,1]
        int ix = (int)floor((sx + 50.0) / 0.5);
        int iy = (int)floor((sy + 50.0) / 0.5);
        int iz = (int)floor((sz + 10.0) / 20.0);
        bool kept = (ix >= 0) & (ix < NXX) & (iy >= 0) & (iy < NXY) & (iz == 0);
        unsigned meta = kept
            ? ((unsigned)iy | ((unsigned)ix << 8) | ((unsigned)pix << 16) | ((unsigned)n << 24))
            : 0xFFFFFFFFu;
        rbcam[rank * DD_ + lane] = make_uint2(meta, __float_as_uint(wgt));
        if (kept)
            atomicAdd(&counts[b * NTILE + (ix >> 3) * NTY + (iy >> 5)], 1);
    }
}

// ---- Kp: exclusive prefix over 1400 bucket counts (1 block, Hillis-Steele)
__global__ __launch_bounds__(1024) void k_prefix(
    const int* __restrict__ counts, int* __restrict__ offsets, int* __restrict__ cursor)
{
    __shared__ int sA[2048], sB[2048];
    const int t = threadIdx.x;
    for (int i = t; i < 2048; i += 1024) sA[i] = (i < NBUCKET) ? counts[i] : 0;
    __syncthreads();
    int* src = sA; int* dst = sB;
    for (int d = 1; d < 2048; d <<= 1) {
        for (int i = t; i < 2048; i += 1024)
            dst[i] = src[i] + (i >= d ? src[i - d] : 0);
        __syncthreads();
        int* tmp = src; src = dst; dst = tmp;
    }
    for (int i = t; i < 2048; i += 1024) {
        if (i == 0) { offsets[0] = 0; cursor[0] = 0; }
        if (i < NBUCKET) {
            offsets[i + 1] = src[i];
            if (i + 1 < NBUCKET) cursor[i + 1] = src[i];
        }
    }
}

// ---- Ks: compact records into per-bucket dense lists
__global__ __launch_bounds__(256) void k_scatter(
    const uint2* __restrict__ recs, int* __restrict__ cursor, uint2* __restrict__ bucketed)
{
    const int i = blockIdx.x * 256 + threadIdx.x;   // NRECS = 246*256 exact
    uint2 r = recs[i];
    if (r.x == 0xFFFFFFFFu) return;
    const int b = i / RECS_PER_BATCH;
    unsigned iy = r.x & 255u, ix = (r.x >> 8) & 255u;
    int bucket = b * NTILE + (int)(ix >> 3) * NTY + (int)(iy >> 5);
    int pos = atomicAdd(&cursor[bucket], 1);
    bucketed[pos] = r;
}

// ---- K2: per (tile, channel-group, batch); reads only its bucket; writes the
//      ENTIRE output (empty tiles stream zeros -> no memset anywhere).
__global__ __launch_bounds__(256) void k2_splat(
    const uint2* __restrict__ bucketed,
    const int* __restrict__ offsets,
    const float* __restrict__ ft,
    float* __restrict__ out)
{
    const int tl = blockIdx.x;           // 0..174
    const int cg = blockIdx.y;           // 0..3
    const int b  = blockIdx.z;           // 0..7
    const int ix0 = (tl / NTY) * TX;
    const int iy0 = (tl % NTY) * TY;
    const int tid = threadIdx.x;
    const int cbase = cg * CG;
    const int bid = b * NTILE + tl;
    const int s = offsets[bid], e = offsets[bid + 1];

    __shared__ float tile[CG][TX * TY];  // 16 KiB

    if (s != e) {
        for (int i = tid; i < CG * TX * TY / 4; i += 256)
            ((float4*)tile)[i] = make_float4(0.f, 0.f, 0.f, 0.f);
        __syncthreads();
        for (int q = s + tid; q < e; q += 256) {
            uint2 r = bucketed[q];
            int iy = r.x & 255, ix = (r.x >> 8) & 255;
            int hw = (r.x >> 16) & 255, n = (r.x >> 24) & 255;
            float wgt = __uint_as_float(r.y);
            int vloc = (ix - ix0) * TY + (iy - iy0);
            const float4* fp = (const float4*)(ft +
                (((size_t)(b * 6 + n) * NPIX + hw) * C_ + cbase));
            #pragma unroll
            for (int qd = 0; qd < CG / 4; ++qd) {
                float4 f = fp[qd];
                atomicAdd(&tile[qd * 4 + 0][vloc], wgt * f.x);
                atomicAdd(&tile[qd * 4 + 1][vloc], wgt * f.y);
                atomicAdd(&tile[qd * 4 + 2][vloc], wgt * f.z);
                atomicAdd(&tile[qd * 4 + 3][vloc], wgt * f.w);
            }
        }
        __syncthreads();
        for (int i = tid; i < CG * TX * (TY / 4); i += 256) {
            int c = i / (TX * TY / 4);
            int rr = i % (TX * TY / 4);
            int ixl = rr / (TY / 4);
            int iyq = (rr % (TY / 4)) * 4;
            int iyg = iy0 + iyq;
            if (iyg < NXY) {
                float4 v = *(const float4*)&tile[c][ixl * TY + iyq];
                *(float4*)&out[(((size_t)b * C_ + cbase + c) * NXX + (ix0 + ixl)) * NXY + iyg] = v;
            }
        }
    } else {
        const float4 z = make_float4(0.f, 0.f, 0.f, 0.f);
        for (int i = tid; i < CG * TX * (TY / 4); i += 256) {
            int c = i / (TX * TY / 4);
            int rr = i % (TX * TY / 4);
            int ixl = rr / (TY / 4);
            int iyq = (rr % (TY / 4)) * 4;
            int iyg = iy0 + iyq;
            if (iyg < NXY)
                *(float4*)&out[(((size_t)b * C_ + cbase + c) * NXX + (ix0 + ixl)) * NXY + iyg] = z;
        }
    }
}

extern "C" void kernel_launch(void* const* d_in, const int* in_sizes, int n_in,
                              void* d_out, int out_size, void* d_ws, size_t ws_size,
                              hipStream_t stream) {
    const float* depth_logits = (const float*)d_in[0];
    const float* feats        = (const float*)d_in[1];
    const float* rots         = (const float*)d_in[2];
    const float* trans        = (const float*)d_in[3];
    const float* Kp           = (const float*)d_in[4];
    const float* Dc           = (const float*)d_in[5];
    const float* xip          = (const float*)d_in[6];
    float* out = (float*)d_out;

    char* ws = (char*)d_ws;
    uint2* recs     = (uint2*)ws;                         ws += (size_t)NRECS * 8;   // 503808
    uint2* bucketed = (uint2*)ws;                         ws += (size_t)NRECS * 8;   // 503808
    int*   counts   = (int*)ws;                           ws += NBUCKET * 4;
    int*   offsets  = (int*)ws;                           ws += (NBUCKET + 4) * 4;
    int*   cursor   = (int*)ws;                           ws += NBUCKET * 4;
    ws = (char*)(((uintptr_t)ws + 255) & ~(uintptr_t)255);
    float* ft       = (float*)ws;                         // 48*176*64*4 = 2162688

    k0_prep <<<dim3(NCAM),        dim3(256),  0, stream>>>(feats, ft, counts);
    k1_geom <<<dim3(NCAM * NPIX), dim3(64),   0, stream>>>(depth_logits, rots, trans,
                                                           Kp, Dc, xip, recs, counts);
    k_prefix<<<dim3(1),           dim3(1024), 0, stream>>>(counts, offsets, cursor);
    k_scatter<<<dim3(NRECS/256),  dim3(256),  0, stream>>>(recs, cursor, bucketed);
    k2_splat<<<dim3(NTILE, C_/CG, 8), dim3(256), 0, stream>>>(bucketed, offsets, ft, out);
}

// Round 6
// 105.794 us; speedup vs baseline: 1.8772x; 1.1081x over previous
//
#include <hip/hip_runtime.h>

#define DD_   41
#define FH_   8
#define FW_   22
#define NPIX  176
#define C_    64
#define NXX   200
#define NXY   200
#define NCAM  48
#define TX    8            // ix rows per slab
#define NTX   25           // 200/8
#define CG    4            // channels per k2 block
#define NCG   16           // 64/4
#define CAP   1024         // records per bucket (geometric bound ~765)
#define NBUCK (8*NTX)      // 200
#define PLANE (TX*NXY)     // 1600 floats = 6400 B contiguous per channel
#define PLANEP 1604        // +4 pad: distinct banks for the 4 channel atomics

// ---- K0: per-camera feats transpose [c][hw]->[hw][c] via LDS; block 0 zeros cnt
__global__ __launch_bounds__(256) void k0_prep(
    const float* __restrict__ feats, float* __restrict__ ft, int* __restrict__ cnt)
{
    const int cam = blockIdx.x;
    const int t = threadIdx.x;
    if (cam == 0 && t < NBUCK) cnt[t] = 0;

    __shared__ float lds[C_ * 177];
    const float* fsrc = feats + (size_t)cam * (C_ * NPIX);
    for (int i4 = t; i4 < (C_ * NPIX) / 4; i4 += 256) {
        float4 v = ((const float4*)fsrc)[i4];
        int c = (i4 * 4) / NPIX, hw = (i4 * 4) % NPIX;
        float* p = &lds[c * 177 + hw];
        p[0] = v.x; p[1] = v.y; p[2] = v.z; p[3] = v.w;
    }
    __syncthreads();
    float* fdst = ft + (size_t)cam * (NPIX * C_);
    for (int i4 = t; i4 < (NPIX * C_) / 4; i4 += 256) {
        int hw = (i4 * 4) / C_, c = (i4 * 4) % C_;
        float4 v;
        v.x = lds[(c + 0) * 177 + hw];
        v.y = lds[(c + 1) * 177 + hw];
        v.z = lds[(c + 2) * 177 + hw];
        v.w = lds[(c + 3) * 177 + hw];
        ((float4*)fdst)[i4] = v;
    }
}

// ---- K1: one 64-thread wave per (cam,pixel); f32 shuffle softmax; f64 geometry
//      (bit-identical chain to the passing rounds); direct scatter into buckets.
__global__ __launch_bounds__(64) void k1_geom(
    const float* __restrict__ depth_logits,
    const float* __restrict__ rots,
    const float* __restrict__ trans,
    const float* __restrict__ Kp,
    const float* __restrict__ Dc,
    const float* __restrict__ xip,
    uint2* __restrict__ bucketed,
    int* __restrict__ cnt)
{
#pragma clang fp contract(off)
    const int gb = blockIdx.x;           // 0..8447
    const int pix = gb % NPIX;
    const int cam = gb / NPIX;
    const int b = cam / 6, n = cam % 6;
    const int lane = threadIdx.x;

    const double u0 = (double)Kp[cam * 4 + 2];
    const double v0 = (double)Kp[cam * 4 + 3];
    const int u0m = (int)floor(u0 / 16.0);
    const int v0m = (int)floor(v0 / 16.0);
    {
        int dx = (pix % FW_) - u0m, dy = (pix / FW_) - v0m;
        if (dx * dx + dy * dy >= 9) return;   // radius=3, int-exact
    }

    // ---- softmax (f32, shuffle reduce; weights smooth — binning below is f64)
    const float* lg = depth_logits + (size_t)cam * DD_ * NPIX + pix;
    float logit = (lane < DD_) ? lg[lane * NPIX] : -3.0e38f;
    float mx = logit;
    for (int s = 32; s; s >>= 1) mx = fmaxf(mx, __shfl_xor(mx, s));
    float ev = (lane < DD_) ? expf(logit - mx) : 0.0f;
    float ssum = ev;
    for (int s = 32; s; s >>= 1) ssum += __shfl_xor(ssum, s);
    const float wgt = ev / ssum;

    // ---- f64 geometry (same expression order as the passing kernel)
    const int h = pix / FW_, w = pix % FW_;
    const double g1 = (double)Kp[cam * 4 + 0];
    const double g2 = (double)Kp[cam * 4 + 1];
    const double k1 = (double)Dc[cam * 4 + 0];
    const double k2 = (double)Dc[cam * 4 + 1];
    const double p1 = (double)Dc[cam * 4 + 2];
    const double p2 = (double)Dc[cam * 4 + 3];
    const double xiv = (double)xip[cam];

    const double px = (double)w * (351.0 / 21.0);
    const double py = (double)h * (127.0 / 7.0);
    const double ppx = (px - u0) / g1;
    const double ppy = (py - v0) / g2;
    double pux = ppx, puy = ppy;
    for (int it = 0; it < 20; ++it) {
        double r2 = pux * pux + puy * puy;
        double r4 = r2 * r2;
        double denom = 1.0 + k1 * r2 + k2 * r4;
        double nx_ = (ppx - 2.0 * p1 * pux * puy - p2 * (r2 + 2.0 * pux * pux)) / denom;
        double ny_ = (ppy - 2.0 * p2 * pux * puy - p1 * (r2 + 2.0 * puy * puy)) / denom;
        pux = nx_; puy = ny_;
    }
    double r2 = pux * pux + puy * puy;
    double aq = r2 + 1.0;
    double bq = 2.0 * xiv * r2;
    double cq = xiv * xiv * r2 - 1.0;
    double Zs = (-bq + sqrt(bq * bq - 4.0 * aq * cq)) / (2.0 * aq);
    double rx = pux * (Zs + xiv);
    double ry = puy * (Zs + xiv);
    double rz = Zs;
    double nrm = sqrt(rx * rx + ry * ry + rz * rz);
    rx /= nrm; ry /= nrm; rz /= nrm;

    if (lane < DD_) {
        const float* R = rots + (size_t)cam * 9;
        double dval = 4.0 + (double)lane;
        double pcx = rx * dval, pcy = ry * dval, pcz = rz * dval;
        double ex = (double)R[0] * pcx + (double)R[1] * pcy + (double)R[2] * pcz + (double)trans[cam * 3 + 0];
        double ey = (double)R[3] * pcx + (double)R[4] * pcy + (double)R[5] * pcz + (double)trans[cam * 3 + 1];
        double ez = (double)R[6] * pcx + (double)R[7] * pcy + (double)R[8] * pcz + (double)trans[cam * 3 + 2];
        double sx = -ex, sy = ey, sz = ez;   // * [-1,1,1]
        int ix = (int)floor((sx + 50.0) / 0.5);
        int iy = (int)floor((sy + 50.0) / 0.5);
        int iz = (int)floor((sz + 10.0) / 20.0);
        if ((ix >= 0) & (ix < NXX) & (iy >= 0) & (iy < NXY) & (iz == 0)) {
            unsigned meta = (unsigned)iy | ((unsigned)ix << 8)
                          | ((unsigned)pix << 16) | ((unsigned)n << 24);
            int bucket = b * NTX + (ix >> 3);
            int pos = atomicAdd(&cnt[bucket], 1);
            if (pos < CAP)
                bucketed[(size_t)bucket * CAP + pos] = make_uint2(meta, __float_as_uint(wgt));
        }
    }
}

// ---- K2: per (slab, channel-group, batch). Accumulate bucket into LDS planes,
//      then write 6400-B contiguous chunks per channel. Covers the ENTIRE output.
__global__ __launch_bounds__(256) void k2_splat(
    const uint2* __restrict__ bucketed,
    const int* __restrict__ cnt,
    const float* __restrict__ ft,
    float* __restrict__ out)
{
    const int slab = blockIdx.x;   // 0..24
    const int cg   = blockIdx.y;   // 0..15
    const int b    = blockIdx.z;   // 0..7
    const int tid  = threadIdx.x;
    const int ix0  = slab * TX;
    const int cbase = cg * CG;
    const int bucket = b * NTX + slab;
    int nrec = cnt[bucket]; if (nrec > CAP) nrec = CAP;

    float* obase = out + (((size_t)b * C_ + cbase) * NXX + ix0) * NXY;

    if (nrec == 0) {   // stream zeros: 4 x 6400B sequential chunks
        const float4 z = make_float4(0.f, 0.f, 0.f, 0.f);
        for (int i4 = tid; i4 < CG * (PLANE / 4); i4 += 256) {
            int c = i4 / (PLANE / 4);
            int off = (i4 % (PLANE / 4)) * 4;
            *(float4*)&obase[(size_t)c * (NXX * NXY) + off] = z;
        }
        return;
    }

    __shared__ float tile[CG][PLANEP];   // 25.7 KiB -> 6 blocks/CU
    for (int i4 = tid; i4 < CG * PLANEP / 4; i4 += 256)
        ((float4*)tile)[i4] = make_float4(0.f, 0.f, 0.f, 0.f);
    __syncthreads();

    const uint2* rb = bucketed + (size_t)bucket * CAP;
    for (int q = tid; q < nrec; q += 256) {
        uint2 r = rb[q];
        int iy = r.x & 255, ix = (r.x >> 8) & 255;
        int hw = (r.x >> 16) & 255, n = (r.x >> 24) & 255;
        float wgt = __uint_as_float(r.y);
        int vloc = (ix - ix0) * NXY + iy;
        float4 f = *(const float4*)(ft + (((size_t)(b * 6 + n) * NPIX + hw) * C_ + cbase));
        atomicAdd(&tile[0][vloc], wgt * f.x);   // banks 0,4,8,12: conflict-free
        atomicAdd(&tile[1][vloc], wgt * f.y);
        atomicAdd(&tile[2][vloc], wgt * f.z);
        atomicAdd(&tile[3][vloc], wgt * f.w);
    }
    __syncthreads();

    for (int i4 = tid; i4 < CG * (PLANE / 4); i4 += 256) {
        int c = i4 / (PLANE / 4);
        int off = (i4 % (PLANE / 4)) * 4;
        *(float4*)&obase[(size_t)c * (NXX * NXY) + off] = *(const float4*)&tile[c][off];
    }
}

extern "C" void kernel_launch(void* const* d_in, const int* in_sizes, int n_in,
                              void* d_out, int out_size, void* d_ws, size_t ws_size,
                              hipStream_t stream) {
    const float* depth_logits = (const float*)d_in[0];
    const float* feats        = (const float*)d_in[1];
    const float* rots         = (const float*)d_in[2];
    const float* trans        = (const float*)d_in[3];
    const float* Kp           = (const float*)d_in[4];
    const float* Dc           = (const float*)d_in[5];
    const float* xip          = (const float*)d_in[6];
    float* out = (float*)d_out;

    char* ws = (char*)d_ws;
    int*   cnt      = (int*)ws;                        ws += 1024;                      // 200 used
    uint2* bucketed = (uint2*)ws;                      ws += (size_t)NBUCK * CAP * 8;   // 1.64 MB
    float* ft       = (float*)ws;                                                       // 2.16 MB

    k0_prep<<<dim3(NCAM),        dim3(256), 0, stream>>>(feats, ft, cnt);
    k1_geom<<<dim3(NCAM * NPIX), dim3(64),  0, stream>>>(depth_logits, rots, trans,
                                                         Kp, Dc, xip, bucketed, cnt);
    k2_splat<<<dim3(NTX, NCG, 8), dim3(256), 0, stream>>>(bucketed, cnt, ft, out);
}

// Round 7
// 76.047 us; speedup vs baseline: 2.6115x; 1.3912x over previous
//
#include <hip/hip_runtime.h>

#define DD_   41
#define FH_   8
#define FW_   22
#define NPIX  176
#define C_    64
#define NXX   200
#define NXY   200
#define NCAM  48
#define TX    8            // ix rows per slab
#define NTX   25           // 200/8
#define CG    8            // channels per k2 block
#define NCG   8            // 64/8
#define CAPC  192          // records per (camera,slab) chunk (bound ~125)
#define PLANE (TX*NXY)     // 1600 floats = 6400 B contiguous per channel
#define PLANEP 1604        // pad: planes offset by 4 banks -> 8 atomics conflict-free
#define NSTAGE (25*41)     // 1025 staged records per camera

// ---- K01: per-camera block. Phase T: feats transpose via LDS. Phase A: f64
//      geometry (bit-identical chain to passing rounds) + LDS-staged records,
//      LDS-atomic counts. Phase B: plain-store per-(cam,slab) counts + compact
//      records into fixed global chunks. NO global atomics anywhere.
__global__ __launch_bounds__(256) void k01_prep(
    const float* __restrict__ depth_logits,
    const float* __restrict__ feats,
    const float* __restrict__ rots,
    const float* __restrict__ trans,
    const float* __restrict__ Kp,
    const float* __restrict__ Dc,
    const float* __restrict__ xip,
    float* __restrict__ ft,
    int* __restrict__ cnt_cam,
    uint2* __restrict__ bucketed)
{
#pragma clang fp contract(off)
    const int cam = blockIdx.x;
    const int n = cam % 6;
    const int t = threadIdx.x;

    __shared__ float lds[C_ * 177];          // 45.3 KB transpose buffer
    __shared__ uint2 rec_stage[NSTAGE];      // 8.2 KB
    __shared__ int cnt_lds[NTX], cur_lds[NTX];

    // Phase T1: feats[cam][c][hw] -> LDS (padded); init staging
    const float* fsrc = feats + (size_t)cam * (C_ * NPIX);
    for (int i4 = t; i4 < (C_ * NPIX) / 4; i4 += 256) {
        float4 v = ((const float4*)fsrc)[i4];
        int c = (i4 * 4) / NPIX, hw = (i4 * 4) % NPIX;
        float* p = &lds[c * 177 + hw];
        p[0] = v.x; p[1] = v.y; p[2] = v.z; p[3] = v.w;
    }
    for (int i = t; i < NSTAGE; i += 256) rec_stage[i] = make_uint2(0xFFFFFFFFu, 0u);
    if (t < NTX) { cnt_lds[t] = 0; cur_lds[t] = 0; }
    __syncthreads();

    // Phase T2: LDS -> ft[cam][hw][c]
    float* fdst = ft + (size_t)cam * (NPIX * C_);
    for (int i4 = t; i4 < (NPIX * C_) / 4; i4 += 256) {
        int hw = (i4 * 4) / C_, c = (i4 * 4) % C_;
        float4 v;
        v.x = lds[(c + 0) * 177 + hw];
        v.y = lds[(c + 1) * 177 + hw];
        v.z = lds[(c + 2) * 177 + hw];
        v.w = lds[(c + 3) * 177 + hw];
        ((float4*)fdst)[i4] = v;
    }

    // Phase A: geometry, thread = pixel
    if (t < NPIX) {
        const double u0 = (double)Kp[cam * 4 + 2];
        const double v0 = (double)Kp[cam * 4 + 3];
        const int u0m = (int)floor(u0 / 16.0);
        const int v0m = (int)floor(v0 / 16.0);
        const int dx = (t % FW_) - u0m, dy = (t / FW_) - v0m;
        if (dx * dx + dy * dy < 9) {          // active (radius=3, int-exact)
            const int sidx = (dy + 2) * 5 + (dx + 2);   // |dx|,|dy|<=2 -> 0..24

            // softmax over 41 bins (f32, serial; weights smooth)
            const float* lg = depth_logits + (size_t)cam * DD_ * NPIX + t;
            float mx = -3.0e38f;
            #pragma unroll
            for (int d = 0; d < DD_; ++d) mx = fmaxf(mx, lg[d * NPIX]);
            float ssum = 0.0f;
            #pragma unroll
            for (int d = 0; d < DD_; ++d) ssum += expf(lg[d * NPIX] - mx);

            // f64 geometry (same expression order as passing rounds)
            const int h = t / FW_, w = t % FW_;
            const double g1 = (double)Kp[cam * 4 + 0];
            const double g2 = (double)Kp[cam * 4 + 1];
            const double k1 = (double)Dc[cam * 4 + 0];
            const double k2 = (double)Dc[cam * 4 + 1];
            const double p1 = (double)Dc[cam * 4 + 2];
            const double p2 = (double)Dc[cam * 4 + 3];
            const double xiv = (double)xip[cam];

            const double px = (double)w * (351.0 / 21.0);
            const double py = (double)h * (127.0 / 7.0);
            const double ppx = (px - u0) / g1;
            const double ppy = (py - v0) / g2;
            double pux = ppx, puy = ppy;
            for (int it = 0; it < 20; ++it) {
                double r2 = pux * pux + puy * puy;
                double r4 = r2 * r2;
                double denom = 1.0 + k1 * r2 + k2 * r4;
                double nx_ = (ppx - 2.0 * p1 * pux * puy - p2 * (r2 + 2.0 * pux * pux)) / denom;
                double ny_ = (ppy - 2.0 * p2 * pux * puy - p1 * (r2 + 2.0 * puy * puy)) / denom;
                pux = nx_; puy = ny_;
            }
            double r2 = pux * pux + puy * puy;
            double aq = r2 + 1.0;
            double bq = 2.0 * xiv * r2;
            double cq = xiv * xiv * r2 - 1.0;
            double Zs = (-bq + sqrt(bq * bq - 4.0 * aq * cq)) / (2.0 * aq);
            double rx = pux * (Zs + xiv);
            double ry = puy * (Zs + xiv);
            double rz = Zs;
            double nrm = sqrt(rx * rx + ry * ry + rz * rz);
            rx /= nrm; ry /= nrm; rz /= nrm;

            const float* R = rots + (size_t)cam * 9;
            const double T0 = (double)trans[cam * 3 + 0];
            const double T1 = (double)trans[cam * 3 + 1];
            const double T2 = (double)trans[cam * 3 + 2];

            for (int d = 0; d < DD_; ++d) {
                float wgt = expf(lg[d * NPIX] - mx) / ssum;
                double dval = 4.0 + (double)d;
                double pcx = rx * dval, pcy = ry * dval, pcz = rz * dval;
                double ex = (double)R[0] * pcx + (double)R[1] * pcy + (double)R[2] * pcz + T0;
                double ey = (double)R[3] * pcx + (double)R[4] * pcy + (double)R[5] * pcz + T1;
                double ez = (double)R[6] * pcx + (double)R[7] * pcy + (double)R[8] * pcz + T2;
                double sx = -ex, sy = ey, sz = ez;   // * [-1,1,1]
                int ix = (int)floor((sx + 50.0) / 0.5);
                int iy = (int)floor((sy + 50.0) / 0.5);
                int iz = (int)floor((sz + 10.0) / 20.0);
                if ((ix >= 0) & (ix < NXX) & (iy >= 0) & (iy < NXY) & (iz == 0)) {
                    atomicAdd(&cnt_lds[ix >> 3], 1);           // LDS atomic: fast
                    unsigned meta = (unsigned)iy | ((unsigned)ix << 8)
                                  | ((unsigned)t << 16) | ((unsigned)n << 24);
                    rec_stage[sidx * DD_ + d] = make_uint2(meta, __float_as_uint(wgt));
                }
            }
        }
    }
    __syncthreads();

    // Phase B: plain-store counts (full overwrite), compact staged recs to chunks
    if (t < NTX) cnt_cam[cam * NTX + t] = min(cnt_lds[t], CAPC);
    __syncthreads();
    for (int i = t; i < NSTAGE; i += 256) {
        uint2 r = rec_stage[i];
        if (r.x != 0xFFFFFFFFu) {
            int slab = ((r.x >> 8) & 255u) >> 3;
            int pos = atomicAdd(&cur_lds[slab], 1);            // LDS atomic
            if (pos < CAPC)
                bucketed[((size_t)cam * NTX + slab) * CAPC + pos] = r;
        }
    }
}

// ---- K2: per (slab, channel-group, batch). Gather 6 per-camera chunks into LDS
//      planes, write 6400-B contiguous runs per channel. Covers ENTIRE output.
__global__ __launch_bounds__(256) void k2_splat(
    const uint2* __restrict__ bucketed,
    const int* __restrict__ cnt_cam,
    const float* __restrict__ ft,
    float* __restrict__ out)
{
    const int slab = blockIdx.x;   // 0..24
    const int cg   = blockIdx.y;   // 0..7
    const int b    = blockIdx.z;   // 0..7
    const int tid  = threadIdx.x;
    const int ix0  = slab * TX;
    const int cbase = cg * CG;

    int nr[6], tot = 0;
    #pragma unroll
    for (int n = 0; n < 6; ++n) {
        int v = cnt_cam[(b * 6 + n) * NTX + slab];
        nr[n] = v < CAPC ? v : CAPC;
        tot += nr[n];
    }

    float* obase = out + (((size_t)b * C_ + cbase) * NXX + ix0) * NXY;

    if (tot == 0) {   // stream zeros: CG x 6400B sequential runs
        const float4 z = make_float4(0.f, 0.f, 0.f, 0.f);
        for (int i4 = tid; i4 < CG * (PLANE / 4); i4 += 256) {
            int c = i4 / (PLANE / 4);
            int off = (i4 % (PLANE / 4)) * 4;
            *(float4*)&obase[(size_t)c * (NXX * NXY) + off] = z;
        }
        return;
    }

    __shared__ float tile[CG][PLANEP];   // 51.3 KiB -> 3 blocks/CU
    for (int i4 = tid; i4 < CG * PLANEP / 4; i4 += 256)
        ((float4*)tile)[i4] = make_float4(0.f, 0.f, 0.f, 0.f);
    __syncthreads();

    #pragma unroll
    for (int n = 0; n < 6; ++n) {
        const uint2* rb = bucketed + ((size_t)(b * 6 + n) * NTX + slab) * CAPC;
        for (int q = tid; q < nr[n]; q += 256) {
            uint2 r = rb[q];
            int iy = r.x & 255, ix = (r.x >> 8) & 255;
            int hw = (r.x >> 16) & 255;
            float wgt = __uint_as_float(r.y);
            int vloc = (ix - ix0) * NXY + iy;
            const float4* fp = (const float4*)(ft +
                (((size_t)(b * 6 + n) * NPIX + hw) * C_ + cbase));
            float4 f0 = fp[0], f1 = fp[1];
            atomicAdd(&tile[0][vloc], wgt * f0.x);   // plane stride 1604: banks
            atomicAdd(&tile[1][vloc], wgt * f0.y);   // +{0,4,..,28} conflict-free
            atomicAdd(&tile[2][vloc], wgt * f0.z);
            atomicAdd(&tile[3][vloc], wgt * f0.w);
            atomicAdd(&tile[4][vloc], wgt * f1.x);
            atomicAdd(&tile[5][vloc], wgt * f1.y);
            atomicAdd(&tile[6][vloc], wgt * f1.z);
            atomicAdd(&tile[7][vloc], wgt * f1.w);
        }
    }
    __syncthreads();

    for (int i4 = tid; i4 < CG * (PLANE / 4); i4 += 256) {
        int c = i4 / (PLANE / 4);
        int off = (i4 % (PLANE / 4)) * 4;
        *(float4*)&obase[(size_t)c * (NXX * NXY) + off] = *(const float4*)&tile[c][off];
    }
}

extern "C" void kernel_launch(void* const* d_in, const int* in_sizes, int n_in,
                              void* d_out, int out_size, void* d_ws, size_t ws_size,
                              hipStream_t stream) {
    const float* depth_logits = (const float*)d_in[0];
    const float* feats        = (const float*)d_in[1];
    const float* rots         = (const float*)d_in[2];
    const float* trans        = (const float*)d_in[3];
    const float* Kp           = (const float*)d_in[4];
    const float* Dc           = (const float*)d_in[5];
    const float* xip          = (const float*)d_in[6];
    float* out = (float*)d_out;

    char* ws = (char*)d_ws;
    int*   cnt_cam  = (int*)ws;                        ws += 8192;                          // 48*25*4=4800 used
    uint2* bucketed = (uint2*)ws;                      ws += (size_t)NCAM * NTX * CAPC * 8; // 1.84 MB
    float* ft       = (float*)ws;                                                           // 2.16 MB

    k01_prep<<<dim3(NCAM), dim3(256), 0, stream>>>(depth_logits, feats, rots, trans,
                                                   Kp, Dc, xip, ft, cnt_cam, bucketed);
    k2_splat<<<dim3(NTX, NCG, 8), dim3(256), 0, stream>>>(bucketed, cnt_cam, ft, out);
}

// Round 8
// 46.112 us; speedup vs baseline: 4.3068x; 1.6492x over previous
//
#include <hip/hip_runtime.h>

#define DD_   41
#define FH_   8
#define FW_   22
#define NPIX  176
#define C_    64
#define NXX   200
#define NXY   200
#define NCAM  48
#define TX    8            // ix rows per slab
#define NTX   25           // 200/8
#define CG    4            // channels per k2 block
#define NCG   16           // 64/4
#define CAPC  192          // records per (camera,slab) chunk (bound ~125)
#define PLANE (TX*NXY)     // 1600 floats = 6400 B contiguous per channel
#define PLANEP 1604        // +4 pad: plane p at bank offset 4p -> atomics conflict-free
#define NACT  25           // active pixels per camera (5x5 disc, u0m=11 v0m=4)
#define NSTAGE (NACT*DD_)  // 1025 fixed staging slots

// ---- K01: one block per camera.
//   T1: feats[c][hw] -> LDS.  T2 (threads>=25) : LDS -> ft[hw][c]  ||  A1 (threads<25):
//   per-pixel f64 undistort + softmax reduce -> LDS.  A2: 1025 (pixel,depth) items
//   in parallel: f64 rotate/bin (bit-identical chain) -> fixed staging slot.
//   B: compact slots -> per-(cam,slab) chunks (LDS atomics only), plain-store counts.
__global__ __launch_bounds__(256) void k01_prep(
    const float* __restrict__ depth_logits,
    const float* __restrict__ feats,
    const float* __restrict__ rots,
    const float* __restrict__ trans,
    const float* __restrict__ Kp,
    const float* __restrict__ Dc,
    const float* __restrict__ xip,
    float* __restrict__ ft,
    int* __restrict__ cnt_cam,
    uint2* __restrict__ bucketed)
{
#pragma clang fp contract(off)
    const int cam = blockIdx.x;
    const int n = cam % 6;
    const int t = threadIdx.x;

    __shared__ float lds[C_ * 177];          // 45.3 KB transpose buffer
    __shared__ uint2 rec_stage[NSTAGE];      // 8.2 KB
    __shared__ double rayx[NACT], rayy[NACT], rayz[NACT];
    __shared__ float mx_l[NACT], ss_l[NACT];
    __shared__ int pix_l[NACT];
    __shared__ int cur_lds[NTX];

    // T1: feats -> LDS (padded rows); init staging + slab cursors
    const float* fsrc = feats + (size_t)cam * (C_ * NPIX);
    for (int i4 = t; i4 < (C_ * NPIX) / 4; i4 += 256) {
        float4 v = ((const float4*)fsrc)[i4];
        int c = (i4 * 4) / NPIX, hw = (i4 * 4) % NPIX;
        float* p = &lds[c * 177 + hw];
        p[0] = v.x; p[1] = v.y; p[2] = v.z; p[3] = v.w;
    }
    for (int i = t; i < NSTAGE; i += 256) rec_stage[i] = make_uint2(0xFFFFFFFFu, 0u);
    if (t < NTX) cur_lds[t] = 0;
    __syncthreads();

    if (t >= NACT) {
        // T2: LDS -> ft[cam][hw][c], threads 25..255
        float* fdst = ft + (size_t)cam * (NPIX * C_);
        for (int i4 = t - NACT; i4 < (NPIX * C_) / 4; i4 += 256 - NACT) {
            int hw = (i4 * 4) / C_, c = (i4 * 4) % C_;
            float4 v;
            v.x = lds[(c + 0) * 177 + hw];
            v.y = lds[(c + 1) * 177 + hw];
            v.z = lds[(c + 2) * 177 + hw];
            v.w = lds[(c + 3) * 177 + hw];
            ((float4*)fdst)[i4] = v;
        }
    } else {
        // A1: per active pixel (5x5 disc): f64 undistort + f32 softmax reduce
        const double u0 = (double)Kp[cam * 4 + 2];
        const double v0 = (double)Kp[cam * 4 + 3];
        const int u0m = (int)floor(u0 / 16.0);
        const int v0m = (int)floor(v0 / 16.0);
        const int dx = t % 5 - 2, dy = t / 5 - 2;
        const int w = u0m + dx, h = v0m + dy;
        const bool ok = (dx * dx + dy * dy < 9) & (w >= 0) & (w < FW_) & (h >= 0) & (h < FH_);
        pix_l[t] = ok ? h * FW_ + w : -1;
        if (ok) {
            const int pix = h * FW_ + w;
            const double g1 = (double)Kp[cam * 4 + 0];
            const double g2 = (double)Kp[cam * 4 + 1];
            const double k1 = (double)Dc[cam * 4 + 0];
            const double k2 = (double)Dc[cam * 4 + 1];
            const double p1 = (double)Dc[cam * 4 + 2];
            const double p2 = (double)Dc[cam * 4 + 3];
            const double xiv = (double)xip[cam];

            const double px = (double)w * (351.0 / 21.0);
            const double py = (double)h * (127.0 / 7.0);
            const double ppx = (px - u0) / g1;
            const double ppy = (py - v0) / g2;
            double pux = ppx, puy = ppy;
            for (int it = 0; it < 20; ++it) {
                double r2 = pux * pux + puy * puy;
                double r4 = r2 * r2;
                double denom = 1.0 + k1 * r2 + k2 * r4;
                double nx_ = (ppx - 2.0 * p1 * pux * puy - p2 * (r2 + 2.0 * pux * pux)) / denom;
                double ny_ = (ppy - 2.0 * p2 * pux * puy - p1 * (r2 + 2.0 * puy * puy)) / denom;
                pux = nx_; puy = ny_;
            }
            double r2 = pux * pux + puy * puy;
            double aq = r2 + 1.0;
            double bq = 2.0 * xiv * r2;
            double cq = xiv * xiv * r2 - 1.0;
            double Zs = (-bq + sqrt(bq * bq - 4.0 * aq * cq)) / (2.0 * aq);
            double rx = pux * (Zs + xiv);
            double ry = puy * (Zs + xiv);
            double rz = Zs;
            double nrm = sqrt(rx * rx + ry * ry + rz * rz);
            rayx[t] = rx / nrm; rayy[t] = ry / nrm; rayz[t] = rz / nrm;

            const float* lg = depth_logits + (size_t)cam * DD_ * NPIX + pix;
            float mxv = -3.0e38f;
            #pragma unroll
            for (int d = 0; d < DD_; ++d) mxv = fmaxf(mxv, lg[d * NPIX]);
            float ssum = 0.0f;
            #pragma unroll
            for (int d = 0; d < DD_; ++d) ssum += expf(lg[d * NPIX] - mxv);
            mx_l[t] = mxv; ss_l[t] = ssum;
        }
    }
    __syncthreads();

    // A2: 1025 (slot, depth) items in parallel; f64 chain identical to passing rounds
    {
        const float* R = rots + (size_t)cam * 9;
        const double R0 = (double)R[0], R1 = (double)R[1], R2 = (double)R[2];
        const double R3 = (double)R[3], R4 = (double)R[4], R5 = (double)R[5];
        const double R6 = (double)R[6], R7 = (double)R[7], R8 = (double)R[8];
        const double T0 = (double)trans[cam * 3 + 0];
        const double T1 = (double)trans[cam * 3 + 1];
        const double T2 = (double)trans[cam * 3 + 2];
        for (int i = t; i < NSTAGE; i += 256) {
            const int s = i / DD_, d = i - s * DD_;
            const int pix = pix_l[s];
            if (pix < 0) continue;
            const float lgv = depth_logits[((size_t)cam * DD_ + d) * NPIX + pix];
            const float wgt = expf(lgv - mx_l[s]) / ss_l[s];
            const double dval = 4.0 + (double)d;
            const double pcx = rayx[s] * dval, pcy = rayy[s] * dval, pcz = rayz[s] * dval;
            const double ex = R0 * pcx + R1 * pcy + R2 * pcz + T0;
            const double ey = R3 * pcx + R4 * pcy + R5 * pcz + T1;
            const double ez = R6 * pcx + R7 * pcy + R8 * pcz + T2;
            const double sx = -ex, sy = ey, sz = ez;   // * [-1,1,1]
            const int ix = (int)floor((sx + 50.0) / 0.5);
            const int iy = (int)floor((sy + 50.0) / 0.5);
            const int iz = (int)floor((sz + 10.0) / 20.0);
            if ((ix >= 0) & (ix < NXX) & (iy >= 0) & (iy < NXY) & (iz == 0)) {
                unsigned meta = (unsigned)iy | ((unsigned)ix << 8)
                              | ((unsigned)pix << 16) | ((unsigned)n << 24);
                rec_stage[i] = make_uint2(meta, __float_as_uint(wgt));
            }
        }
    }
    __syncthreads();

    // B: compact staged records into per-(cam,slab) chunks; LDS atomics only
    for (int i = t; i < NSTAGE; i += 256) {
        uint2 r = rec_stage[i];
        if (r.x != 0xFFFFFFFFu) {
            int slab = ((r.x >> 8) & 255u) >> 3;
            int pos = atomicAdd(&cur_lds[slab], 1);
            if (pos < CAPC)
                bucketed[((size_t)cam * NTX + slab) * CAPC + pos] = r;
        }
    }
    __syncthreads();
    if (t < NTX) cnt_cam[cam * NTX + t] = min(cur_lds[t], CAPC);   // plain store
}

// ---- K2: per (slab, cg, batch). Interleaved 6-camera chunk processing (parallel
//      latency chains), LDS plane accumulate, 6400-B contiguous writes. Covers
//      the ENTIRE output every call (no memset, no global atomics).
__global__ __launch_bounds__(256) void k2_splat(
    const uint2* __restrict__ bucketed,
    const int* __restrict__ cnt_cam,
    const float* __restrict__ ft,
    float* __restrict__ out)
{
    const int slab = blockIdx.x;   // 0..24
    const int cg   = blockIdx.y;   // 0..15
    const int b    = blockIdx.z;   // 0..7
    const int tid  = threadIdx.x;
    const int ix0  = slab * TX;
    const int cbase = cg * CG;

    int nr[6], maxnr = 0;
    #pragma unroll
    for (int n = 0; n < 6; ++n) {
        int v = cnt_cam[(b * 6 + n) * NTX + slab];
        nr[n] = v < CAPC ? v : CAPC;
        maxnr = nr[n] > maxnr ? nr[n] : maxnr;
    }

    float* obase = out + (((size_t)b * C_ + cbase) * NXX + ix0) * NXY;

    if (maxnr == 0) {   // stream zeros: CG x 6400B sequential runs
        const float4 z = make_float4(0.f, 0.f, 0.f, 0.f);
        for (int i4 = tid; i4 < CG * (PLANE / 4); i4 += 256) {
            int c = i4 / (PLANE / 4);
            int off = (i4 % (PLANE / 4)) * 4;
            *(float4*)&obase[(size_t)c * (NXX * NXY) + off] = z;
        }
        return;
    }

    __shared__ float tile[CG][PLANEP];   // 25.7 KiB -> 6 blocks/CU
    for (int i4 = tid; i4 < CG * PLANEP / 4; i4 += 256)
        ((float4*)tile)[i4] = make_float4(0.f, 0.f, 0.f, 0.f);
    __syncthreads();

    // one flattened loop; 6 independent rec->ft->atomic chains in flight
    for (int q = tid; q < maxnr; q += 256) {
        #pragma unroll
        for (int n = 0; n < 6; ++n) {
            if (q < nr[n]) {
                uint2 r = bucketed[((size_t)(b * 6 + n) * NTX + slab) * CAPC + q];
                int iy = r.x & 255, ix = (r.x >> 8) & 255;
                int hw = (r.x >> 16) & 255;
                float wgt = __uint_as_float(r.y);
                int vloc = (ix - ix0) * NXY + iy;
                float4 f = *(const float4*)(ft +
                    (((size_t)(b * 6 + n) * NPIX + hw) * C_ + cbase));
                atomicAdd(&tile[0][vloc], wgt * f.x);
                atomicAdd(&tile[1][vloc], wgt * f.y);
                atomicAdd(&tile[2][vloc], wgt * f.z);
                atomicAdd(&tile[3][vloc], wgt * f.w);
            }
        }
    }
    __syncthreads();

    for (int i4 = tid; i4 < CG * (PLANE / 4); i4 += 256) {
        int c = i4 / (PLANE / 4);
        int off = (i4 % (PLANE / 4)) * 4;
        *(float4*)&obase[(size_t)c * (NXX * NXY) + off] = *(const float4*)&tile[c][off];
    }
}

extern "C" void kernel_launch(void* const* d_in, const int* in_sizes, int n_in,
                              void* d_out, int out_size, void* d_ws, size_t ws_size,
                              hipStream_t stream) {
    const float* depth_logits = (const float*)d_in[0];
    const float* feats        = (const float*)d_in[1];
    const float* rots         = (const float*)d_in[2];
    const float* trans        = (const float*)d_in[3];
    const float* Kp           = (const float*)d_in[4];
    const float* Dc           = (const float*)d_in[5];
    const float* xip          = (const float*)d_in[6];
    float* out = (float*)d_out;

    char* ws = (char*)d_ws;
    int*   cnt_cam  = (int*)ws;                        ws += 8192;                          // 48*25*4 used
    uint2* bucketed = (uint2*)ws;                      ws += (size_t)NCAM * NTX * CAPC * 8; // 1.84 MB
    float* ft       = (float*)ws;                                                           // 2.16 MB

    k01_prep<<<dim3(NCAM), dim3(256), 0, stream>>>(depth_logits, feats, rots, trans,
                                                   Kp, Dc, xip, ft, cnt_cam, bucketed);
    k2_splat<<<dim3(NTX, NCG, 8), dim3(256), 0, stream>>>(bucketed, cnt_cam, ft, out);
}